// Round 1
// baseline (622.779 us; speedup 1.0000x reference)
//
#include <hip/hip_runtime.h>
#include <cstdint>
#include <cstddef>

#define DD 128
#define KK 32
constexpr float EPS = 1e-8f;

typedef __bf16 bf16x8 __attribute__((ext_vector_type(8)));
typedef float f32x4 __attribute__((ext_vector_type(4)));

__device__ __forceinline__ unsigned short f2bf(float x) {
    union { float f; uint32_t u; } v; v.f = x;
    uint32_t r = v.u + 0x7FFFu + ((v.u >> 16) & 1u);   // RNE
    return (unsigned short)(r >> 16);
}
__device__ __forceinline__ float bflo(uint32_t w) {
    union { uint32_t u; float f; } v; v.u = w << 16; return v.f;
}
__device__ __forceinline__ float bfhi(uint32_t w) {
    union { uint32_t u; float f; } v; v.u = w & 0xFFFF0000u; return v.f;
}

// ---------- pre-kernel 1: fp32 -> bf16 (row-major, 4 elems/thread) ----------
__global__ void cvt_kernel(const float* __restrict__ src,
                           unsigned short* __restrict__ dst, int n) {
    int i = (blockIdx.x * blockDim.x + threadIdx.x) * 4;
    if (i >= n) return;
    float4 f = *reinterpret_cast<const float4*>(src + i);
    ushort4 o;
    o.x = f2bf(f.x); o.y = f2bf(f.y); o.z = f2bf(f.z); o.w = f2bf(f.w);
    *reinterpret_cast<ushort4*>(dst + i) = o;
}

// ---------- pre-kernel 2: W[k][d][e] fp32 -> Wt[k][e][d] bf16 ----------
__global__ void wtrans_kernel(const float* __restrict__ W,
                              unsigned short* __restrict__ Wt) {
    __shared__ float tile[32][33];
    int k = blockIdx.z;
    int d0 = blockIdx.y * 32, e0 = blockIdx.x * 32;
    int tx = threadIdx.x & 31, ty = threadIdx.x >> 5;   // 256 thr: ty 0..7
    const float* Wk = W + (size_t)k * DD * DD;
    #pragma unroll
    for (int r = ty; r < 32; r += 8)
        tile[r][tx] = Wk[(size_t)(d0 + r) * DD + e0 + tx];
    __syncthreads();
    unsigned short* Wtk = Wt + (size_t)k * DD * DD;
    #pragma unroll
    for (int r = ty; r < 32; r += 8)
        Wtk[(size_t)(e0 + r) * DD + d0 + tx] = f2bf(tile[tx][r]);
}

// ---------- main fused kernel ----------
// grid (N/128, K), block 256. Wave w: rows (w>>1)*64.., cols (w&1)*64..
__global__ __launch_bounds__(256) void ntn_main(
    const unsigned short* __restrict__ X1b, const unsigned short* __restrict__ X2b,
    const unsigned short* __restrict__ W1t, const unsigned short* __restrict__ W2t,
    const float* __restrict__ V, const float* __restrict__ bias,
    float* __restrict__ out, int N)
{
    const int ntile = blockIdx.x;
    const int k     = blockIdx.y;
    const int tid   = threadIdx.x;
    const int wave  = tid >> 6;
    const int lane  = tid & 63;
    const int m     = lane & 15;
    const int quad  = lane >> 4;
    const int wrow  = (wave >> 1) * 64;
    const int wcol  = (wave & 1) * 64;
    const int n_base = ntile * 128 + wrow;

    f32x4 acc1[4][4], acc2[4][4];
    #pragma unroll
    for (int i = 0; i < 4; ++i)
        #pragma unroll
        for (int j = 0; j < 4; ++j) {
            acc1[i][j] = f32x4{0.f, 0.f, 0.f, 0.f};
            acc2[i][j] = f32x4{0.f, 0.f, 0.f, 0.f};
        }

    const unsigned short* w1p = W1t + (size_t)k * DD * DD;
    const unsigned short* w2p = W2t + (size_t)k * DD * DD;

    #pragma unroll
    for (int ks = 0; ks < 4; ++ks) {
        const int koff = ks * 32 + quad * 8;
        bf16x8 a1[4], a2[4];
        #pragma unroll
        for (int rt = 0; rt < 4; ++rt) {
            const size_t row = (size_t)(n_base + rt * 16 + m);
            a1[rt] = *reinterpret_cast<const bf16x8*>(X1b + row * DD + koff);
            a2[rt] = *reinterpret_cast<const bf16x8*>(X2b + row * DD + koff);
        }
        #pragma unroll
        for (int et = 0; et < 4; ++et) {
            const size_t e = (size_t)(wcol + et * 16 + m);
            bf16x8 b1 = *reinterpret_cast<const bf16x8*>(w1p + e * DD + koff);
            bf16x8 b2 = *reinterpret_cast<const bf16x8*>(w2p + e * DD + koff);
            #pragma unroll
            for (int rt = 0; rt < 4; ++rt) {
                acc1[rt][et] = __builtin_amdgcn_mfma_f32_16x16x32_bf16(a1[rt], b1, acc1[rt][et], 0, 0, 0);
                acc2[rt][et] = __builtin_amdgcn_mfma_f32_16x16x32_bf16(a2[rt], b2, acc2[rt][et], 0, 0, 0);
            }
        }
    }

    // ---- epilogue: per-row dot / |x1t| / |x2t| over this wave's 64 cols ----
    __shared__ float sDot[2][128], sN1[2][128], sN2[2][128];

    #pragma unroll
    for (int rt = 0; rt < 4; ++rt) {
        float pd[4] = {0.f, 0.f, 0.f, 0.f};
        float p1[4] = {0.f, 0.f, 0.f, 0.f};
        float p2[4] = {0.f, 0.f, 0.f, 0.f};
        #pragma unroll
        for (int et = 0; et < 4; ++et)
            #pragma unroll
            for (int reg = 0; reg < 4; ++reg) {
                float c1 = acc1[rt][et][reg];
                float c2 = acc2[rt][et][reg];
                pd[reg] += c1 * c2;
                p1[reg] += c1 * c1;
                p2[reg] += c2 * c2;
            }
        #pragma unroll
        for (int reg = 0; reg < 4; ++reg) {
            float d = pd[reg], a = p1[reg], c = p2[reg];
            #pragma unroll
            for (int off = 1; off < 16; off <<= 1) {
                d += __shfl_xor(d, off, 64);
                a += __shfl_xor(a, off, 64);
                c += __shfl_xor(c, off, 64);
            }
            if (m == 0) {
                int row = wrow + rt * 16 + quad * 4 + reg;
                int h = wave & 1;
                sDot[h][row] = d;
                sN1[h][row]  = a;
                sN2[h][row]  = c;
            }
        }
    }
    __syncthreads();

    if (tid < 128) {
        const int row = tid;
        const size_t n = (size_t)ntile * 128 + row;
        float dot = sDot[0][row] + sDot[1][row];
        float n1 = sqrtf(sN1[0][row] + sN1[1][row]);
        float n2 = sqrtf(sN2[0][row] + sN2[1][row]);
        float part1 = dot / (fmaxf(n1, EPS) * fmaxf(n2, EPS));

        // part2 = x1[n]·V[k][0:128] + x2[n]·V[k][128:256]  (x from bf16, V fp32)
        const float* Vk = V + (size_t)k * 2 * DD;
        const uint4* x1v = reinterpret_cast<const uint4*>(X1b + n * DD);
        const uint4* x2v = reinterpret_cast<const uint4*>(X2b + n * DD);
        float p2 = 0.f;
        #pragma unroll
        for (int t = 0; t < 16; ++t) {
            uint4 u1 = x1v[t];
            uint4 u2 = x2v[t];
            const float* v1 = Vk + t * 8;
            const float* v2 = Vk + DD + t * 8;
            p2 += bflo(u1.x) * v1[0] + bfhi(u1.x) * v1[1]
                + bflo(u1.y) * v1[2] + bfhi(u1.y) * v1[3]
                + bflo(u1.z) * v1[4] + bfhi(u1.z) * v1[5]
                + bflo(u1.w) * v1[6] + bfhi(u1.w) * v1[7];
            p2 += bflo(u2.x) * v2[0] + bfhi(u2.x) * v2[1]
                + bflo(u2.y) * v2[2] + bfhi(u2.y) * v2[3]
                + bflo(u2.z) * v2[4] + bfhi(u2.z) * v2[5]
                + bflo(u2.w) * v2[6] + bfhi(u2.w) * v2[7];
        }
        out[n * KK + k] = fmaxf(part1 + p2 + bias[k], 0.f);
    }
}

extern "C" void kernel_launch(void* const* d_in, const int* in_sizes, int n_in,
                              void* d_out, int out_size, void* d_ws, size_t ws_size,
                              hipStream_t stream) {
    const float* x1 = (const float*)d_in[0];
    const float* x2 = (const float*)d_in[1];
    const float* W1 = (const float*)d_in[2];
    const float* W2 = (const float*)d_in[3];
    const float* V  = (const float*)d_in[4];
    const float* b  = (const float*)d_in[5];
    float* out = (float*)d_out;

    const int N = in_sizes[0] / DD;   // 32768

    unsigned short* X1b = (unsigned short*)d_ws;
    unsigned short* X2b = X1b + (size_t)N * DD;
    unsigned short* W1t = X2b + (size_t)N * DD;
    unsigned short* W2t = W1t + (size_t)KK * DD * DD;

    const int nx = N * DD;
    const int cvt_blocks = (nx / 4 + 255) / 256;
    cvt_kernel<<<cvt_blocks, 256, 0, stream>>>(x1, X1b, nx);
    cvt_kernel<<<cvt_blocks, 256, 0, stream>>>(x2, X2b, nx);
    wtrans_kernel<<<dim3(4, 4, KK), 256, 0, stream>>>(W1, W1t);
    wtrans_kernel<<<dim3(4, 4, KK), 256, 0, stream>>>(W2, W2t);

    ntn_main<<<dim3(N / 128, KK), 256, 0, stream>>>(X1b, X2b, W1t, W2t, V, b, out, N);
}

// Round 2
// 250.224 us; speedup vs baseline: 2.4889x; 2.4889x over previous
//
#include <hip/hip_runtime.h>
#include <cstdint>
#include <cstddef>

#define DD 128
#define KK 32
constexpr float EPS = 1e-8f;

typedef __bf16 bf16x8 __attribute__((ext_vector_type(8)));
typedef float f32x4 __attribute__((ext_vector_type(4)));

__device__ __forceinline__ unsigned short f2bf(float x) {
    union { float f; uint32_t u; } v; v.f = x;
    uint32_t r = v.u + 0x7FFFu + ((v.u >> 16) & 1u);   // RNE
    return (unsigned short)(r >> 16);
}

// ---------------- pre-kernel 1: x fp32 [N][128] -> Xf bf16 fragment layout --
// Xf[rg][c][m][8] where row = rg*16+m, d = c*8+j  (c = ks*4+quad)
// offset = rg*2048 + c*128 + m*8. A wave's fragment load = base + lane*8 elems.
__global__ __launch_bounds__(256) void cvt_kernel(const float* __restrict__ src,
                                                  __bf16* __restrict__ dst) {
    int idx = blockIdx.x * 256 + threadIdx.x;   // [0, N*16)
    int row = idx >> 4, c = idx & 15;
    const float* p = src + (size_t)row * DD + c * 8;
    float4 f0 = *reinterpret_cast<const float4*>(p);
    float4 f1 = *reinterpret_cast<const float4*>(p + 4);
    ushort4 o0, o1;
    o0.x = f2bf(f0.x); o0.y = f2bf(f0.y); o0.z = f2bf(f0.z); o0.w = f2bf(f0.w);
    o1.x = f2bf(f1.x); o1.y = f2bf(f1.y); o1.z = f2bf(f1.z); o1.w = f2bf(f1.w);
    size_t off = (size_t)(row >> 4) * 2048 + (size_t)c * 128 + (size_t)(row & 15) * 8;
    *reinterpret_cast<ushort4*>(dst + off)     = o0;
    *reinterpret_cast<ushort4*>(dst + off + 4) = o1;
}

// ---------------- pre-kernel 2: W fp32 [K][D][E] -> Wf bf16 B-fragment layout
// Wf[k][eg][c][m][8]: value = W[k][d=c*8+j][e=eg*16+m]
__global__ __launch_bounds__(256) void wf_kernel(const float* __restrict__ W,
                                                 __bf16* __restrict__ Wf) {
    int idx = blockIdx.x * 256 + threadIdx.x;   // [0, 65536)
    int m  = idx & 15;
    int c  = (idx >> 4) & 15;
    int eg = (idx >> 8) & 7;
    int k  = idx >> 11;
    const float* Wk = W + (size_t)k * DD * DD;
    int e = eg * 16 + m;
    ushort4 o0, o1;
    o0.x = f2bf(Wk[(size_t)(c * 8 + 0) * DD + e]);
    o0.y = f2bf(Wk[(size_t)(c * 8 + 1) * DD + e]);
    o0.z = f2bf(Wk[(size_t)(c * 8 + 2) * DD + e]);
    o0.w = f2bf(Wk[(size_t)(c * 8 + 3) * DD + e]);
    o1.x = f2bf(Wk[(size_t)(c * 8 + 4) * DD + e]);
    o1.y = f2bf(Wk[(size_t)(c * 8 + 5) * DD + e]);
    o1.z = f2bf(Wk[(size_t)(c * 8 + 6) * DD + e]);
    o1.w = f2bf(Wk[(size_t)(c * 8 + 7) * DD + e]);
    size_t off = ((size_t)(k * 8 + eg)) * 2048 + (size_t)c * 128 + (size_t)m * 8;
    *reinterpret_cast<ushort4*>(Wf + off)     = o0;
    *reinterpret_cast<ushort4*>(Wf + off + 4) = o1;
}

// ---------------- pre-kernel 3: V fp32 [K][2D][1] -> Vf bf16 B-fragment layout
// Vf[ct][ks][lane][8]: value = V[k=ct*16+m][f=ks*32+quad*8+j]
__global__ void vf_kernel(const float* __restrict__ V, __bf16* __restrict__ Vf) {
    int idx = blockIdx.x * 256 + threadIdx.x;   // [0, 1024)
    int m    = idx & 15;
    int quad = (idx >> 4) & 3;
    int ks   = (idx >> 6) & 7;
    int ct   = idx >> 9;
    const float* p = V + (size_t)(ct * 16 + m) * 256 + ks * 32 + quad * 8;
    ushort4 o0, o1;
    o0.x = f2bf(p[0]); o0.y = f2bf(p[1]); o0.z = f2bf(p[2]); o0.w = f2bf(p[3]);
    o1.x = f2bf(p[4]); o1.y = f2bf(p[5]); o1.z = f2bf(p[6]); o1.w = f2bf(p[7]);
    size_t off = (size_t)idx * 8;
    *reinterpret_cast<ushort4*>(Vf + off)     = o0;
    *reinterpret_cast<ushort4*>(Vf + off + 4) = o1;
}

// ---------------- part2 GEMM: p2w[n][k] = xcat[n] . V[k]  (N x 32, K=256) ----
__global__ __launch_bounds__(256) void part2_kernel(
    const __bf16* __restrict__ X1f, const __bf16* __restrict__ X2f,
    const __bf16* __restrict__ Vf, float* __restrict__ p2w) {
    const int wave = threadIdx.x >> 6, lane = threadIdx.x & 63;
    const int m = lane & 15, quad = lane >> 4;
    const int rg0 = blockIdx.x * 16 + wave * 4;   // 64 rows per wave

    f32x4 acc[4][2];
    #pragma unroll
    for (int rt = 0; rt < 4; ++rt)
        #pragma unroll
        for (int ct = 0; ct < 2; ++ct) acc[rt][ct] = f32x4{0.f, 0.f, 0.f, 0.f};

    #pragma unroll
    for (int ks = 0; ks < 8; ++ks) {
        const __bf16* Xs = (ks < 4) ? X1f : X2f;
        const int kss = ks & 3;
        bf16x8 a[4];
        #pragma unroll
        for (int rt = 0; rt < 4; ++rt)
            a[rt] = *reinterpret_cast<const bf16x8*>(
                Xs + (size_t)(rg0 + rt) * 2048 + kss * 512 + lane * 8);
        #pragma unroll
        for (int ct = 0; ct < 2; ++ct) {
            bf16x8 b = *reinterpret_cast<const bf16x8*>(
                Vf + ((size_t)(ct * 8 + ks) * 64 + lane) * 8);
            #pragma unroll
            for (int rt = 0; rt < 4; ++rt)
                acc[rt][ct] = __builtin_amdgcn_mfma_f32_16x16x32_bf16(a[rt], b, acc[rt][ct], 0, 0, 0);
        }
    }
    const int row0 = blockIdx.x * 256 + wave * 64;
    #pragma unroll
    for (int rt = 0; rt < 4; ++rt)
        #pragma unroll
        for (int ct = 0; ct < 2; ++ct)
            #pragma unroll
            for (int reg = 0; reg < 4; ++reg)
                p2w[(size_t)(row0 + rt * 16 + quad * 4 + reg) * KK + ct * 16 + m] = acc[rt][ct][reg];
}

// ---------------- main fused kernel ----------------
// grid (K, N/128) — k fastest for output-line merging & W L2 residency.
__global__ __launch_bounds__(256, 2) void ntn_main(
    const __bf16* __restrict__ X1f, const __bf16* __restrict__ X2f,
    const __bf16* __restrict__ W1f, const __bf16* __restrict__ W2f,
    const float* __restrict__ p2w, const float* __restrict__ bias,
    float* __restrict__ out)
{
    const int k     = blockIdx.x;
    const int ntile = blockIdx.y;
    const int tid   = threadIdx.x;
    const int wave  = tid >> 6;
    const int lane  = tid & 63;
    const int m     = lane & 15;
    const int quad  = lane >> 4;
    const int wrow  = (wave >> 1) * 64;
    const int wcol  = (wave & 1) * 64;

    f32x4 acc1[4][4], acc2[4][4];
    #pragma unroll
    for (int i = 0; i < 4; ++i)
        #pragma unroll
        for (int j = 0; j < 4; ++j) {
            acc1[i][j] = f32x4{0.f, 0.f, 0.f, 0.f};
            acc2[i][j] = f32x4{0.f, 0.f, 0.f, 0.f};
        }

    const __bf16* w1p = W1f + (size_t)k * DD * DD;
    const __bf16* w2p = W2f + (size_t)k * DD * DD;
    const int rgb = ntile * 8 + (wrow >> 4);
    const int egb = wcol >> 4;

    #pragma unroll
    for (int ks = 0; ks < 4; ++ks) {
        bf16x8 a1[4], a2[4];
        #pragma unroll
        for (int rt = 0; rt < 4; ++rt) {
            const size_t off = (size_t)(rgb + rt) * 2048 + ks * 512 + lane * 8;
            a1[rt] = *reinterpret_cast<const bf16x8*>(X1f + off);
            a2[rt] = *reinterpret_cast<const bf16x8*>(X2f + off);
        }
        #pragma unroll
        for (int et = 0; et < 4; ++et) {
            const size_t boff = (size_t)(egb + et) * 2048 + ks * 512 + lane * 8;
            bf16x8 b1 = *reinterpret_cast<const bf16x8*>(w1p + boff);
            bf16x8 b2 = *reinterpret_cast<const bf16x8*>(w2p + boff);
            #pragma unroll
            for (int rt = 0; rt < 4; ++rt) {
                acc1[rt][et] = __builtin_amdgcn_mfma_f32_16x16x32_bf16(a1[rt], b1, acc1[rt][et], 0, 0, 0);
                acc2[rt][et] = __builtin_amdgcn_mfma_f32_16x16x32_bf16(a2[rt], b2, acc2[rt][et], 0, 0, 0);
            }
        }
    }

    // ---- epilogue: per-row dot / |x1t|^2 / |x2t|^2 over this wave's 64 cols
    __shared__ float sDot[2][128], sN1[2][128], sN2[2][128];

    #pragma unroll
    for (int rt = 0; rt < 4; ++rt) {
        float pd[4] = {0.f, 0.f, 0.f, 0.f};
        float p1[4] = {0.f, 0.f, 0.f, 0.f};
        float p2[4] = {0.f, 0.f, 0.f, 0.f};
        #pragma unroll
        for (int et = 0; et < 4; ++et)
            #pragma unroll
            for (int reg = 0; reg < 4; ++reg) {
                float c1 = acc1[rt][et][reg];
                float c2 = acc2[rt][et][reg];
                pd[reg] += c1 * c2;
                p1[reg] += c1 * c1;
                p2[reg] += c2 * c2;
            }
        #pragma unroll
        for (int reg = 0; reg < 4; ++reg) {
            float d = pd[reg], a = p1[reg], c = p2[reg];
            #pragma unroll
            for (int off = 1; off < 16; off <<= 1) {
                d += __shfl_xor(d, off, 64);
                a += __shfl_xor(a, off, 64);
                c += __shfl_xor(c, off, 64);
            }
            if (m == 0) {
                int row = wrow + rt * 16 + quad * 4 + reg;
                int h = wave & 1;
                sDot[h][row] = d;
                sN1[h][row]  = a;
                sN2[h][row]  = c;
            }
        }
    }
    __syncthreads();

    if (tid < 128) {
        const int row = tid;
        const size_t n = (size_t)ntile * 128 + row;
        float dot = sDot[0][row] + sDot[1][row];
        float n1 = sqrtf(sN1[0][row] + sN1[1][row]);
        float n2 = sqrtf(sN2[0][row] + sN2[1][row]);
        float part1 = dot / (fmaxf(n1, EPS) * fmaxf(n2, EPS));
        float p2 = p2w[n * KK + k];
        out[n * KK + k] = fmaxf(part1 + p2 + bias[k], 0.f);
    }
}

extern "C" void kernel_launch(void* const* d_in, const int* in_sizes, int n_in,
                              void* d_out, int out_size, void* d_ws, size_t ws_size,
                              hipStream_t stream) {
    const float* x1 = (const float*)d_in[0];
    const float* x2 = (const float*)d_in[1];
    const float* W1 = (const float*)d_in[2];
    const float* W2 = (const float*)d_in[3];
    const float* V  = (const float*)d_in[4];
    const float* b  = (const float*)d_in[5];
    float* out = (float*)d_out;

    const int N = in_sizes[0] / DD;   // 32768

    __bf16* X1f = (__bf16*)d_ws;
    __bf16* X2f = X1f + (size_t)N * DD;
    __bf16* W1f = X2f + (size_t)N * DD;
    __bf16* W2f = W1f + (size_t)KK * DD * DD;
    __bf16* Vf  = W2f + (size_t)KK * DD * DD;
    float*  p2w = (float*)(Vf + (size_t)KK * 2 * DD);

    cvt_kernel<<<N * 16 / 256, 256, 0, stream>>>(x1, X1f);
    cvt_kernel<<<N * 16 / 256, 256, 0, stream>>>(x2, X2f);
    wf_kernel<<<KK * DD * DD / 8 / 256, 256, 0, stream>>>(W1, W1f);
    wf_kernel<<<KK * DD * DD / 8 / 256, 256, 0, stream>>>(W2, W2f);
    vf_kernel<<<4, 256, 0, stream>>>(V, Vf);
    part2_kernel<<<N / 256, 256, 0, stream>>>(X1f, X2f, Vf, p2w);

    ntn_main<<<dim3(KK, N / 128), 256, 0, stream>>>(X1f, X2f, W1f, W2f, p2w, b, out);
}

// Round 3
// 244.006 us; speedup vs baseline: 2.5523x; 1.0255x over previous
//
#include <hip/hip_runtime.h>
#include <cstdint>
#include <cstddef>

#define DD 128
#define KK 32
constexpr float EPS = 1e-8f;

typedef __bf16 bf16x8 __attribute__((ext_vector_type(8)));
typedef float f32x4 __attribute__((ext_vector_type(4)));

__device__ __forceinline__ unsigned short f2bf(float x) {
    union { float f; uint32_t u; } v; v.f = x;
    uint32_t r = v.u + 0x7FFFu + ((v.u >> 16) & 1u);   // RNE
    return (unsigned short)(r >> 16);
}
__device__ __forceinline__ __bf16 f2bf16(float x) {
    unsigned short u = f2bf(x);
    __bf16 r; __builtin_memcpy(&r, &u, 2); return r;
}

// ---------------- pre-kernel 1: x fp32 [N][128] -> Xf bf16 fragment layout --
// Xf[rg][c][m][8] where row = rg*16+m, d = c*8+j  (c = ks*4+quad)
// offset = rg*2048 + c*128 + m*8. A wave's fragment load = base + lane*8 elems.
// Handles BOTH x1 and x2 in one launch (blockIdx >= half -> x2).
__global__ __launch_bounds__(256) void cvt_kernel(
    const float* __restrict__ x1, const float* __restrict__ x2,
    __bf16* __restrict__ X1f, __bf16* __restrict__ X2f, int half_blocks) {
    int bb = blockIdx.x;
    const float* src; __bf16* dst;
    if (bb >= half_blocks) { src = x2; dst = X2f; bb -= half_blocks; }
    else                   { src = x1; dst = X1f; }
    int idx = bb * 256 + threadIdx.x;   // [0, N*16)
    int row = idx >> 4, c = idx & 15;
    const float* p = src + (size_t)row * DD + c * 8;
    float4 f0 = *reinterpret_cast<const float4*>(p);
    float4 f1 = *reinterpret_cast<const float4*>(p + 4);
    ushort4 o0, o1;
    o0.x = f2bf(f0.x); o0.y = f2bf(f0.y); o0.z = f2bf(f0.z); o0.w = f2bf(f0.w);
    o1.x = f2bf(f1.x); o1.y = f2bf(f1.y); o1.z = f2bf(f1.z); o1.w = f2bf(f1.w);
    size_t off = (size_t)(row >> 4) * 2048 + (size_t)c * 128 + (size_t)(row & 15) * 8;
    *reinterpret_cast<ushort4*>(dst + off)     = o0;
    *reinterpret_cast<ushort4*>(dst + off + 4) = o1;
}

// ---------------- pre-kernel 2: W fp32 [K][D][E] -> Wf bf16 B-fragment layout
// Wf[k][eg][c][m][8]: value = W[k][d=c*8+j][e=eg*16+m]. Both W1 and W2.
__global__ __launch_bounds__(256) void wf_kernel(
    const float* __restrict__ W1, const float* __restrict__ W2,
    __bf16* __restrict__ W1f, __bf16* __restrict__ W2f, int half_blocks) {
    int bb = blockIdx.x;
    const float* W; __bf16* Wf;
    if (bb >= half_blocks) { W = W2; Wf = W2f; bb -= half_blocks; }
    else                   { W = W1; Wf = W1f; }
    int idx = bb * 256 + threadIdx.x;   // [0, 65536)
    int m  = idx & 15;
    int c  = (idx >> 4) & 15;
    int eg = (idx >> 8) & 7;
    int k  = idx >> 11;
    const float* Wk = W + (size_t)k * DD * DD;
    int e = eg * 16 + m;
    ushort4 o0, o1;
    o0.x = f2bf(Wk[(size_t)(c * 8 + 0) * DD + e]);
    o0.y = f2bf(Wk[(size_t)(c * 8 + 1) * DD + e]);
    o0.z = f2bf(Wk[(size_t)(c * 8 + 2) * DD + e]);
    o0.w = f2bf(Wk[(size_t)(c * 8 + 3) * DD + e]);
    o1.x = f2bf(Wk[(size_t)(c * 8 + 4) * DD + e]);
    o1.y = f2bf(Wk[(size_t)(c * 8 + 5) * DD + e]);
    o1.z = f2bf(Wk[(size_t)(c * 8 + 6) * DD + e]);
    o1.w = f2bf(Wk[(size_t)(c * 8 + 7) * DD + e]);
    size_t off = ((size_t)(k * 8 + eg)) * 2048 + (size_t)c * 128 + (size_t)m * 8;
    *reinterpret_cast<ushort4*>(Wf + off)     = o0;
    *reinterpret_cast<ushort4*>(Wf + off + 4) = o1;
}

// ---------------- part2 GEMM: p2w[n][k] = xcat[n] . V[k]  (N x 32, K=256) ----
// V converted to B-fragment in-register (V is 32 KB, L2-hot).
__global__ __launch_bounds__(256) void part2_kernel(
    const __bf16* __restrict__ X1f, const __bf16* __restrict__ X2f,
    const float* __restrict__ V, float* __restrict__ p2w) {
    const int wave = threadIdx.x >> 6, lane = threadIdx.x & 63;
    const int m = lane & 15, quad = lane >> 4;
    const int rg0 = blockIdx.x * 16 + wave * 4;   // 64 rows per wave

    f32x4 acc[4][2];
    #pragma unroll
    for (int rt = 0; rt < 4; ++rt)
        #pragma unroll
        for (int ct = 0; ct < 2; ++ct) acc[rt][ct] = f32x4{0.f, 0.f, 0.f, 0.f};

    #pragma unroll
    for (int ks = 0; ks < 8; ++ks) {
        const __bf16* Xs = (ks < 4) ? X1f : X2f;
        const int kss = ks & 3;
        bf16x8 a[4];
        #pragma unroll
        for (int rt = 0; rt < 4; ++rt)
            a[rt] = *reinterpret_cast<const bf16x8*>(
                Xs + (size_t)(rg0 + rt) * 2048 + kss * 512 + lane * 8);
        #pragma unroll
        for (int ct = 0; ct < 2; ++ct) {
            // b[lane][j] = V[k=ct*16+m][f=ks*32+quad*8+j]
            const float* p = V + (size_t)(ct * 16 + m) * 256 + ks * 32 + quad * 8;
            float4 v0 = *reinterpret_cast<const float4*>(p);
            float4 v1 = *reinterpret_cast<const float4*>(p + 4);
            bf16x8 b;
            b[0] = f2bf16(v0.x); b[1] = f2bf16(v0.y); b[2] = f2bf16(v0.z); b[3] = f2bf16(v0.w);
            b[4] = f2bf16(v1.x); b[5] = f2bf16(v1.y); b[6] = f2bf16(v1.z); b[7] = f2bf16(v1.w);
            #pragma unroll
            for (int rt = 0; rt < 4; ++rt)
                acc[rt][ct] = __builtin_amdgcn_mfma_f32_16x16x32_bf16(a[rt], b, acc[rt][ct], 0, 0, 0);
        }
    }
    const int row0 = blockIdx.x * 256 + wave * 64;
    #pragma unroll
    for (int rt = 0; rt < 4; ++rt)
        #pragma unroll
        for (int ct = 0; ct < 2; ++ct)
            #pragma unroll
            for (int reg = 0; reg < 4; ++reg)
                p2w[(size_t)(row0 + rt * 16 + quad * 4 + reg) * KK + ct * 16 + m] = acc[rt][ct][reg];
}

// ---------------- main fused kernel ----------------
// 1D grid of 8192. XCD-aware decode (blocks dispatch round-robin over 8 XCDs):
//   xcd = b&7, k = (b>>3)&31 (FAST: all 32 k co-resident -> output lines merge,
//   X tile stays hot), ntile = xcd*32 + (b>>8) (each XCD owns a disjoint
//   ntile range; W 2 MB stays L2-resident per XCD all kernel).
__global__ __launch_bounds__(256, 2) void ntn_main(
    const __bf16* __restrict__ X1f, const __bf16* __restrict__ X2f,
    const __bf16* __restrict__ W1f, const __bf16* __restrict__ W2f,
    const float* __restrict__ p2w, const float* __restrict__ bias,
    float* __restrict__ out, int nt_per_xcd)
{
    const int b     = blockIdx.x;
    const int xcd   = b & 7;
    const int j     = b >> 3;
    const int k     = j & 31;
    const int ntile = xcd * nt_per_xcd + (j >> 5);
    const int tid   = threadIdx.x;
    const int wave  = tid >> 6;
    const int lane  = tid & 63;
    const int m     = lane & 15;
    const int quad  = lane >> 4;
    const int wrow  = (wave >> 1) * 64;
    const int wcol  = (wave & 1) * 64;

    f32x4 acc1[4][4], acc2[4][4];
    #pragma unroll
    for (int i = 0; i < 4; ++i)
        #pragma unroll
        for (int jj = 0; jj < 4; ++jj) {
            acc1[i][jj] = f32x4{0.f, 0.f, 0.f, 0.f};
            acc2[i][jj] = f32x4{0.f, 0.f, 0.f, 0.f};
        }

    const __bf16* w1p = W1f + (size_t)k * DD * DD;
    const __bf16* w2p = W2f + (size_t)k * DD * DD;
    const int rgb = ntile * 8 + (wrow >> 4);
    const int egb = wcol >> 4;

    #pragma unroll
    for (int ks = 0; ks < 4; ++ks) {
        bf16x8 a1[4], a2[4];
        #pragma unroll
        for (int rt = 0; rt < 4; ++rt) {
            const size_t off = (size_t)(rgb + rt) * 2048 + ks * 512 + lane * 8;
            a1[rt] = *reinterpret_cast<const bf16x8*>(X1f + off);
            a2[rt] = *reinterpret_cast<const bf16x8*>(X2f + off);
        }
        #pragma unroll
        for (int et = 0; et < 4; ++et) {
            const size_t boff = (size_t)(egb + et) * 2048 + ks * 512 + lane * 8;
            bf16x8 b1 = *reinterpret_cast<const bf16x8*>(w1p + boff);
            bf16x8 b2 = *reinterpret_cast<const bf16x8*>(w2p + boff);
            #pragma unroll
            for (int rt = 0; rt < 4; ++rt) {
                acc1[rt][et] = __builtin_amdgcn_mfma_f32_16x16x32_bf16(a1[rt], b1, acc1[rt][et], 0, 0, 0);
                acc2[rt][et] = __builtin_amdgcn_mfma_f32_16x16x32_bf16(a2[rt], b2, acc2[rt][et], 0, 0, 0);
            }
        }
    }

    // ---- epilogue: per-row dot / |x1t|^2 / |x2t|^2 over this wave's 64 cols
    __shared__ float sDot[2][128], sN1[2][128], sN2[2][128];

    #pragma unroll
    for (int rt = 0; rt < 4; ++rt) {
        float pd[4] = {0.f, 0.f, 0.f, 0.f};
        float p1[4] = {0.f, 0.f, 0.f, 0.f};
        float p2[4] = {0.f, 0.f, 0.f, 0.f};
        #pragma unroll
        for (int et = 0; et < 4; ++et)
            #pragma unroll
            for (int reg = 0; reg < 4; ++reg) {
                float c1 = acc1[rt][et][reg];
                float c2 = acc2[rt][et][reg];
                pd[reg] += c1 * c2;
                p1[reg] += c1 * c1;
                p2[reg] += c2 * c2;
            }
        #pragma unroll
        for (int reg = 0; reg < 4; ++reg) {
            float d = pd[reg], a = p1[reg], c = p2[reg];
            #pragma unroll
            for (int off = 1; off < 16; off <<= 1) {
                d += __shfl_xor(d, off, 64);
                a += __shfl_xor(a, off, 64);
                c += __shfl_xor(c, off, 64);
            }
            if (m == 0) {
                int row = wrow + rt * 16 + quad * 4 + reg;
                int h = wave & 1;
                sDot[h][row] = d;
                sN1[h][row]  = a;
                sN2[h][row]  = c;
            }
        }
    }
    __syncthreads();

    if (tid < 128) {
        const int row = tid;
        const size_t n = (size_t)ntile * 128 + row;
        float dot = sDot[0][row] + sDot[1][row];
        float n1 = sqrtf(sN1[0][row] + sN1[1][row]);
        float n2 = sqrtf(sN2[0][row] + sN2[1][row]);
        float part1 = dot / (fmaxf(n1, EPS) * fmaxf(n2, EPS));
        float p2 = p2w[n * KK + k];
        out[n * KK + k] = fmaxf(part1 + p2 + bias[k], 0.f);
    }
}

extern "C" void kernel_launch(void* const* d_in, const int* in_sizes, int n_in,
                              void* d_out, int out_size, void* d_ws, size_t ws_size,
                              hipStream_t stream) {
    const float* x1 = (const float*)d_in[0];
    const float* x2 = (const float*)d_in[1];
    const float* W1 = (const float*)d_in[2];
    const float* W2 = (const float*)d_in[3];
    const float* V  = (const float*)d_in[4];
    const float* b  = (const float*)d_in[5];
    float* out = (float*)d_out;

    const int N = in_sizes[0] / DD;   // 32768

    __bf16* X1f = (__bf16*)d_ws;
    __bf16* X2f = X1f + (size_t)N * DD;
    __bf16* W1f = X2f + (size_t)N * DD;
    __bf16* W2f = W1f + (size_t)KK * DD * DD;
    float*  p2w = (float*)(W2f + (size_t)KK * DD * DD);

    const int cvt_half = N * 16 / 256;
    cvt_kernel<<<cvt_half * 2, 256, 0, stream>>>(x1, x2, X1f, X2f, cvt_half);
    const int wf_half = KK * DD * DD / 8 / 256;
    wf_kernel<<<wf_half * 2, 256, 0, stream>>>(W1, W2, W1f, W2f, wf_half);
    part2_kernel<<<N / 256, 256, 0, stream>>>(X1f, X2f, V, p2w);

    const int ntiles = N / 128;
    ntn_main<<<ntiles * KK, 256, 0, stream>>>(X1f, X2f, W1f, W2f, p2w, b, out, ntiles / 8);
}